// Round 1
// baseline (5806.430 us; speedup 1.0000x reference)
//
#include <hip/hip_runtime.h>
#include <math.h>

#define DIMD 512
#define NSEQ 4096
#define NHEAD 8
#define HD 64
#define TOPK 16

// ---------------------------------------------------------------------------
// Per-row LayerNorm stats: mean and 1/sqrt(var+eps). One block per row.
// ---------------------------------------------------------------------------
__global__ __launch_bounds__(256) void ln_stats_kernel(
    const float* __restrict__ X, float2* __restrict__ S)
{
    int r = blockIdx.x;
    int t = threadIdx.x;
    const float* xr = X + (size_t)r * DIMD;
    float a = xr[t], b = xr[t + 256];
    float s = a + b;
    float sq = a * a + b * b;
    #pragma unroll
    for (int off = 32; off > 0; off >>= 1) {
        s  += __shfl_down(s, off, 64);
        sq += __shfl_down(sq, off, 64);
    }
    __shared__ float red[8];
    int wv = t >> 6, ln = t & 63;
    if (ln == 0) { red[wv] = s; red[wv + 4] = sq; }
    __syncthreads();
    if (t == 0) {
        float st  = red[0] + red[1] + red[2] + red[3];
        float sqt = red[4] + red[5] + red[6] + red[7];
        float mean = st * (1.0f / DIMD);
        float var  = sqt * (1.0f / DIMD) - mean * mean;
        float inv  = 1.0f / sqrtf(var + 1e-5f);
        S[r] = make_float2(mean, inv);
    }
}

// ---------------------------------------------------------------------------
// fp32 GEMM: C[M x Nn] = act(LN(A) @ W + bias) (+ R)
//   A: [M x Kd] row-major, W: [Kd x Nn] row-major.
//   If lnstats != nullptr, A is normalized on load:
//     a = (a - mean[row]) * inv[row] * lng[k] + lnb[k]
//   gelu: exact GELU applied after bias (before residual).
//   R: optional residual added last. C may alias R (tile-local, same thread).
// Block: 256 threads, tile 64x64, BK=32; each thread computes 4x4.
// ---------------------------------------------------------------------------
__global__ __launch_bounds__(256) void gemm_f32(
    const float* __restrict__ A, const float* __restrict__ W,
    const float* __restrict__ bias, const float* __restrict__ R,
    float* __restrict__ C, int Kd, int Nn, int gelu,
    const float2* __restrict__ lnstats,
    const float* __restrict__ lng, const float* __restrict__ lnb)
{
    __shared__ float As[32][64];   // transposed: As[k][m]
    __shared__ float Ws[32][64];   // Ws[k][n]
    int n0 = blockIdx.x * 64;
    int m0 = blockIdx.y * 64;
    int t  = threadIdx.x;
    int tr = t >> 4, tc = t & 15;
    float acc[4][4] = {};

    for (int k0 = 0; k0 < Kd; k0 += 32) {
        #pragma unroll
        for (int qq = 0; qq < 2; ++qq) {
            int idx = t * 2 + qq;              // 0..511
            int r   = idx >> 3;                // 0..63
            int c4  = idx & 7;                 // 0..7
            float4 av = *(const float4*)&A[(size_t)(m0 + r) * Kd + k0 + c4 * 4];
            if (lnstats) {
                float2 st = lnstats[m0 + r];
                float4 gv = *(const float4*)&lng[k0 + c4 * 4];
                float4 bv = *(const float4*)&lnb[k0 + c4 * 4];
                av.x = (av.x - st.x) * st.y * gv.x + bv.x;
                av.y = (av.y - st.x) * st.y * gv.y + bv.y;
                av.z = (av.z - st.x) * st.y * gv.z + bv.z;
                av.w = (av.w - st.x) * st.y * gv.w + bv.w;
            }
            As[c4 * 4 + 0][r] = av.x;
            As[c4 * 4 + 1][r] = av.y;
            As[c4 * 4 + 2][r] = av.z;
            As[c4 * 4 + 3][r] = av.w;
            int kr  = idx >> 4;                // 0..31
            int nc4 = idx & 15;                // 0..15
            *(float4*)&Ws[kr][nc4 * 4] =
                *(const float4*)&W[(size_t)(k0 + kr) * Nn + n0 + nc4 * 4];
        }
        __syncthreads();
        #pragma unroll
        for (int kk = 0; kk < 32; ++kk) {
            float4 a = *(const float4*)&As[kk][tr * 4];
            float4 b = *(const float4*)&Ws[kk][tc * 4];
            acc[0][0] += a.x * b.x; acc[0][1] += a.x * b.y;
            acc[0][2] += a.x * b.z; acc[0][3] += a.x * b.w;
            acc[1][0] += a.y * b.x; acc[1][1] += a.y * b.y;
            acc[1][2] += a.y * b.z; acc[1][3] += a.y * b.w;
            acc[2][0] += a.z * b.x; acc[2][1] += a.z * b.y;
            acc[2][2] += a.z * b.z; acc[2][3] += a.z * b.w;
            acc[3][0] += a.w * b.x; acc[3][1] += a.w * b.y;
            acc[3][2] += a.w * b.z; acc[3][3] += a.w * b.w;
        }
        __syncthreads();
    }

    float4 bb = *(const float4*)&bias[n0 + tc * 4];
    #pragma unroll
    for (int i = 0; i < 4; ++i) {
        int row = m0 + tr * 4 + i;
        float4 o;
        o.x = acc[i][0] + bb.x;
        o.y = acc[i][1] + bb.y;
        o.z = acc[i][2] + bb.z;
        o.w = acc[i][3] + bb.w;
        if (gelu) {
            o.x = 0.5f * o.x * (1.0f + erff(o.x * 0.70710678118654752f));
            o.y = 0.5f * o.y * (1.0f + erff(o.y * 0.70710678118654752f));
            o.z = 0.5f * o.z * (1.0f + erff(o.z * 0.70710678118654752f));
            o.w = 0.5f * o.w * (1.0f + erff(o.w * 0.70710678118654752f));
        }
        if (R) {
            float4 rv = *(const float4*)&R[(size_t)row * Nn + n0 + tc * 4];
            o.x += rv.x; o.y += rv.y; o.z += rv.z; o.w += rv.w;
        }
        *(float4*)&C[(size_t)row * Nn + n0 + tc * 4] = o;
    }
}

// ---------------------------------------------------------------------------
// Fused: logits (fp32) + streaming top-16 + softmax + V-gather.
// Grid: (B*H*16) blocks, 256 threads; 1 thread = 1 query.
// ---------------------------------------------------------------------------
__global__ __launch_bounds__(256) void topk_attn_kernel(
    const float* __restrict__ Qm, const float* __restrict__ Km,
    const float* __restrict__ Vm, float* __restrict__ Om)
{
    int bid = blockIdx.x;
    int qc  = bid & 15;
    int h   = (bid >> 4) & 7;
    int b   = bid >> 7;
    int t   = threadIdx.x;
    int q   = qc * 256 + t;
    size_t qoff = ((size_t)(b * NSEQ + q)) * DIMD + h * HD;

    float4 qv[16];
    #pragma unroll
    for (int i = 0; i < 16; ++i) qv[i] = *(const float4*)&Qm[qoff + i * 4];

    float vals[TOPK];
    int   idxs[TOPK];
    #pragma unroll
    for (int i = 0; i < TOPK; ++i) { vals[i] = -INFINITY; idxs[i] = 0; }

    __shared__ float4 Ks[64 * 16];    // 64 keys x 64 dims
    size_t kbase = ((size_t)b * NSEQ) * DIMD + h * HD;

    for (int t0 = 0; t0 < NSEQ; t0 += 64) {
        #pragma unroll
        for (int qq = 0; qq < 4; ++qq) {
            int idx = t + 256 * qq;          // 0..1023
            int r   = idx >> 4;              // 0..63
            int c4  = idx & 15;              // 0..15
            Ks[r * 16 + c4] =
                *(const float4*)&Km[kbase + (size_t)(t0 + r) * DIMD + c4 * 4];
        }
        __syncthreads();
        for (int j = 0; j < 64; ++j) {
            float a0 = 0.f, a1 = 0.f, a2 = 0.f, a3 = 0.f;
            #pragma unroll
            for (int d4 = 0; d4 < 16; ++d4) {
                float4 kv = Ks[j * 16 + d4];
                a0 += qv[d4].x * kv.x;
                a1 += qv[d4].y * kv.y;
                a2 += qv[d4].z * kv.z;
                a3 += qv[d4].w * kv.w;
            }
            float sc = ((a0 + a1) + (a2 + a3)) * 0.125f;
            if (sc > vals[0]) {
                // shift out entries below the insertion point
                #pragma unroll
                for (int i = 0; i < TOPK - 1; ++i) {
                    bool mv = vals[i + 1] < sc;
                    vals[i] = mv ? vals[i + 1] : vals[i];
                    idxs[i] = mv ? idxs[i + 1] : idxs[i];
                }
                // place sc at the last position whose value < sc
                #pragma unroll
                for (int i = 0; i < TOPK; ++i) {
                    bool put = (vals[i] < sc) &&
                               ((i == TOPK - 1) || !(vals[i + 1] < sc));
                    if (put) { vals[i] = sc; idxs[i] = t0 + j; }
                }
            }
        }
        __syncthreads();
    }

    // softmax over the 16 kept values (vals ascending; max at [15])
    float m = vals[TOPK - 1];
    float w[TOPK];
    float wsum = 0.f;
    #pragma unroll
    for (int i = 0; i < TOPK; ++i) { w[i] = expf(vals[i] - m); wsum += w[i]; }
    float inv = 1.0f / wsum;
    const float* vp[TOPK];
    #pragma unroll
    for (int i = 0; i < TOPK; ++i) {
        vp[i] = &Vm[((size_t)(b * NSEQ + idxs[i])) * DIMD + h * HD];
        w[i] *= inv;
    }
    float* op = Om + qoff;
    #pragma unroll
    for (int d4 = 0; d4 < 16; ++d4) {
        float4 accv = make_float4(0.f, 0.f, 0.f, 0.f);
        #pragma unroll
        for (int i = 0; i < TOPK; ++i) {
            float4 vv = *(const float4*)&vp[i][d4 * 4];
            accv.x += w[i] * vv.x;
            accv.y += w[i] * vv.y;
            accv.z += w[i] * vv.z;
            accv.w += w[i] * vv.w;
        }
        *(float4*)&op[d4 * 4] = accv;
    }
}

// ---------------------------------------------------------------------------
extern "C" void kernel_launch(void* const* d_in, const int* in_sizes, int n_in,
                              void* d_out, int out_size, void* d_ws, size_t ws_size,
                              hipStream_t stream)
{
    (void)in_sizes; (void)n_in; (void)out_size; (void)ws_size;
    const float* x    = (const float*)d_in[0];
    const float* q_w  = (const float*)d_in[1];
    const float* q_b  = (const float*)d_in[2];
    const float* k_w  = (const float*)d_in[3];
    const float* k_b  = (const float*)d_in[4];
    const float* v_w  = (const float*)d_in[5];
    const float* v_b  = (const float*)d_in[6];
    const float* o_w  = (const float*)d_in[7];
    const float* o_b  = (const float*)d_in[8];
    const float* ln1g = (const float*)d_in[9];
    const float* ln1b = (const float*)d_in[10];
    const float* ln2g = (const float*)d_in[11];
    const float* ln2b = (const float*)d_in[12];
    const float* ff1w = (const float*)d_in[13];
    const float* ff1b = (const float*)d_in[14];
    const float* ff2w = (const float*)d_in[15];
    const float* ff2b = (const float*)d_in[16];
    float* out = (float*)d_out;
    float* ws  = (float*)d_ws;

    const size_t SZ = (size_t)8192 * DIMD;   // 4M floats
    float*  Qb    = ws;                      // [8192 x 512]
    float*  Kb    = ws + SZ;
    float*  Vb    = ws + 2 * SZ;
    float*  attn  = ws + 3 * SZ;
    float2* stats = (float2*)(ws + 4 * SZ);  // 8192 float2
    float*  ffb   = ws;                      // [8192 x 2048], reuses Qb..attn

    dim3 g512(8, 128);    // Nn/64, M/64

    // LN1 stats, then Q/K/V projections with LN fused into the A-load.
    ln_stats_kernel<<<8192, 256, 0, stream>>>(x, stats);
    gemm_f32<<<g512, 256, 0, stream>>>(x, q_w, q_b, nullptr, Qb,
                                       512, 512, 0, stats, ln1g, ln1b);
    gemm_f32<<<g512, 256, 0, stream>>>(x, k_w, k_b, nullptr, Kb,
                                       512, 512, 0, stats, ln1g, ln1b);
    gemm_f32<<<g512, 256, 0, stream>>>(x, v_w, v_b, nullptr, Vb,
                                       512, 512, 0, stats, ln1g, ln1b);

    // Fused top-k attention -> attn [8192 x 512]
    topk_attn_kernel<<<256, 256, 0, stream>>>(Qb, Kb, Vb, attn);

    // x2 = x + attn @ o_w + o_b   -> d_out
    gemm_f32<<<g512, 256, 0, stream>>>(attn, o_w, o_b, x, out,
                                       512, 512, 0, nullptr, nullptr, nullptr);

    // LN2 stats from x2, FFN with LN fused; ff1 -> ffb (gelu), then
    // out = x2 + ffb @ ff2_w + ff2_b (in-place residual on d_out).
    ln_stats_kernel<<<8192, 256, 0, stream>>>(out, stats);
    gemm_f32<<<dim3(32, 128), 256, 0, stream>>>(out, ff1w, ff1b, nullptr, ffb,
                                                512, 2048, 1, stats, ln2g, ln2b);
    gemm_f32<<<g512, 256, 0, stream>>>(ffb, ff2w, ff2b, out, out,
                                       2048, 512, 0, nullptr, nullptr, nullptr);
}

// Round 2
// 2384.139 us; speedup vs baseline: 2.4354x; 2.4354x over previous
//
#include <hip/hip_runtime.h>
#include <math.h>

#define DIMD 512
#define NSEQ 4096
#define NHEAD 8
#define HD 64
#define TOPK 16
#define NSPLIT 4
#define CHUNK (NSEQ / NSPLIT)   // 1024 keys per split

// ---------------------------------------------------------------------------
// Per-row LayerNorm stats: mean and 1/sqrt(var+eps). One block per row.
// ---------------------------------------------------------------------------
__global__ __launch_bounds__(256) void ln_stats_kernel(
    const float* __restrict__ X, float2* __restrict__ S)
{
    int r = blockIdx.x;
    int t = threadIdx.x;
    const float* xr = X + (size_t)r * DIMD;
    float a = xr[t], b = xr[t + 256];
    float s = a + b;
    float sq = a * a + b * b;
    #pragma unroll
    for (int off = 32; off > 0; off >>= 1) {
        s  += __shfl_down(s, off, 64);
        sq += __shfl_down(sq, off, 64);
    }
    __shared__ float red[8];
    int wv = t >> 6, ln = t & 63;
    if (ln == 0) { red[wv] = s; red[wv + 4] = sq; }
    __syncthreads();
    if (t == 0) {
        float st  = red[0] + red[1] + red[2] + red[3];
        float sqt = red[4] + red[5] + red[6] + red[7];
        float mean = st * (1.0f / DIMD);
        float var  = sqt * (1.0f / DIMD) - mean * mean;
        float inv  = 1.0f / sqrtf(var + 1e-5f);
        S[r] = make_float2(mean, inv);
    }
}

// ---------------------------------------------------------------------------
// fp32 GEMM: C[M x Nn] = act(LN(A) @ W + bias) (+ R)
// Block: 256 threads, tile 64x64, BK=32; each thread computes 4x4.
// ---------------------------------------------------------------------------
__global__ __launch_bounds__(256) void gemm_f32(
    const float* __restrict__ A, const float* __restrict__ W,
    const float* __restrict__ bias, const float* __restrict__ R,
    float* __restrict__ C, int Kd, int Nn, int gelu,
    const float2* __restrict__ lnstats,
    const float* __restrict__ lng, const float* __restrict__ lnb)
{
    __shared__ float As[32][64];   // transposed: As[k][m]
    __shared__ float Ws[32][64];   // Ws[k][n]
    int n0 = blockIdx.x * 64;
    int m0 = blockIdx.y * 64;
    int t  = threadIdx.x;
    int tr = t >> 4, tc = t & 15;
    float acc[4][4] = {};

    for (int k0 = 0; k0 < Kd; k0 += 32) {
        #pragma unroll
        for (int qq = 0; qq < 2; ++qq) {
            int idx = t * 2 + qq;              // 0..511
            int r   = idx >> 3;                // 0..63
            int c4  = idx & 7;                 // 0..7
            float4 av = *(const float4*)&A[(size_t)(m0 + r) * Kd + k0 + c4 * 4];
            if (lnstats) {
                float2 st = lnstats[m0 + r];
                float4 gv = *(const float4*)&lng[k0 + c4 * 4];
                float4 bv = *(const float4*)&lnb[k0 + c4 * 4];
                av.x = (av.x - st.x) * st.y * gv.x + bv.x;
                av.y = (av.y - st.x) * st.y * gv.y + bv.y;
                av.z = (av.z - st.x) * st.y * gv.z + bv.z;
                av.w = (av.w - st.x) * st.y * gv.w + bv.w;
            }
            As[c4 * 4 + 0][r] = av.x;
            As[c4 * 4 + 1][r] = av.y;
            As[c4 * 4 + 2][r] = av.z;
            As[c4 * 4 + 3][r] = av.w;
            int kr  = idx >> 4;                // 0..31
            int nc4 = idx & 15;                // 0..15
            *(float4*)&Ws[kr][nc4 * 4] =
                *(const float4*)&W[(size_t)(k0 + kr) * Nn + n0 + nc4 * 4];
        }
        __syncthreads();
        #pragma unroll
        for (int kk = 0; kk < 32; ++kk) {
            float4 a = *(const float4*)&As[kk][tr * 4];
            float4 b = *(const float4*)&Ws[kk][tc * 4];
            acc[0][0] += a.x * b.x; acc[0][1] += a.x * b.y;
            acc[0][2] += a.x * b.z; acc[0][3] += a.x * b.w;
            acc[1][0] += a.y * b.x; acc[1][1] += a.y * b.y;
            acc[1][2] += a.y * b.z; acc[1][3] += a.y * b.w;
            acc[2][0] += a.z * b.x; acc[2][1] += a.z * b.y;
            acc[2][2] += a.z * b.z; acc[2][3] += a.z * b.w;
            acc[3][0] += a.w * b.x; acc[3][1] += a.w * b.y;
            acc[3][2] += a.w * b.z; acc[3][3] += a.w * b.w;
        }
        __syncthreads();
    }

    float4 bb = *(const float4*)&bias[n0 + tc * 4];
    #pragma unroll
    for (int i = 0; i < 4; ++i) {
        int row = m0 + tr * 4 + i;
        float4 o;
        o.x = acc[i][0] + bb.x;
        o.y = acc[i][1] + bb.y;
        o.z = acc[i][2] + bb.z;
        o.w = acc[i][3] + bb.w;
        if (gelu) {
            o.x = 0.5f * o.x * (1.0f + erff(o.x * 0.70710678118654752f));
            o.y = 0.5f * o.y * (1.0f + erff(o.y * 0.70710678118654752f));
            o.z = 0.5f * o.z * (1.0f + erff(o.z * 0.70710678118654752f));
            o.w = 0.5f * o.w * (1.0f + erff(o.w * 0.70710678118654752f));
        }
        if (R) {
            float4 rv = *(const float4*)&R[(size_t)row * Nn + n0 + tc * 4];
            o.x += rv.x; o.y += rv.y; o.z += rv.z; o.w += rv.w;
        }
        *(float4*)&C[(size_t)row * Nn + n0 + tc * 4] = o;
    }
}

// ---------------------------------------------------------------------------
// Partial top-16 over one key chunk. 1 thread = 1 query, streams CHUNK keys.
// Grid: B*H*NSPLIT*16 blocks; bid = (((b*8 + h)*NSPLIT + s)*16 + qc).
// Writes sorted-ascending (val, idx) lists (16 per query per split).
// ---------------------------------------------------------------------------
__global__ __launch_bounds__(256, 4) void topk_partial_kernel(
    const float* __restrict__ Qm, const float* __restrict__ Km,
    float2* __restrict__ P01, float2* __restrict__ P23)
{
    int bid = blockIdx.x;
    int qc  = bid & 15;
    int s   = (bid >> 4) & 3;
    int h   = (bid >> 6) & 7;
    int b   = bid >> 9;
    int t   = threadIdx.x;
    int q   = qc * 256 + t;
    size_t qg   = (size_t)b * NSEQ + q;
    size_t qoff = qg * DIMD + h * HD;

    float4 qv[16];
    #pragma unroll
    for (int i = 0; i < 16; ++i) qv[i] = *(const float4*)&Qm[qoff + i * 4];

    float vals[TOPK];
    int   idxs[TOPK];
    #pragma unroll
    for (int i = 0; i < TOPK; ++i) { vals[i] = -INFINITY; idxs[i] = 0; }

    __shared__ float4 Ks[64 * 16];    // 64 keys x 64 dims
    size_t kbase = ((size_t)b * NSEQ) * DIMD + h * HD;
    int k0base = s * CHUNK;

    for (int t0 = 0; t0 < CHUNK; t0 += 64) {
        #pragma unroll
        for (int qq = 0; qq < 4; ++qq) {
            int idx = t + 256 * qq;          // 0..1023
            int r   = idx >> 4;              // 0..63
            int c4  = idx & 15;              // 0..15
            Ks[r * 16 + c4] = *(const float4*)
                &Km[kbase + (size_t)(k0base + t0 + r) * DIMD + c4 * 4];
        }
        __syncthreads();
        for (int j = 0; j < 64; ++j) {
            float a0 = 0.f, a1 = 0.f, a2 = 0.f, a3 = 0.f;
            #pragma unroll
            for (int d4 = 0; d4 < 16; ++d4) {
                float4 kv = Ks[j * 16 + d4];
                a0 += qv[d4].x * kv.x;
                a1 += qv[d4].y * kv.y;
                a2 += qv[d4].z * kv.z;
                a3 += qv[d4].w * kv.w;
            }
            float sc = ((a0 + a1) + (a2 + a3)) * 0.125f;
            if (sc > vals[0]) {
                int kidx = k0base + t0 + j;
                // fused shift+place: p = #(vals < sc); new[i<p-1]=old[i+1],
                // new[p-1]=sc, new[i>=p]=old[i]. Strict compares => lower
                // index wins ties (matches lax.top_k).
                #pragma unroll
                for (int i = 0; i < TOPK - 1; ++i) {
                    bool up   = vals[i + 1] < sc;
                    bool here = vals[i]     < sc;
                    float nv = up ? vals[i + 1] : (here ? sc   : vals[i]);
                    int   ni = up ? idxs[i + 1] : (here ? kidx : idxs[i]);
                    vals[i] = nv; idxs[i] = ni;
                }
                if (vals[TOPK - 1] < sc) { vals[TOPK - 1] = sc; idxs[TOPK - 1] = kidx; }
            }
        }
        __syncthreads();
    }

    float2* P = (s < 2) ? P01 : P23;
    size_t base = (((qg * NHEAD + h) * 2) + (s & 1)) * TOPK;
    #pragma unroll
    for (int i = 0; i < TOPK; ++i)
        P[base + i] = make_float2(vals[i], __int_as_float(idxs[i]));
}

// ---------------------------------------------------------------------------
// Merge 4 sorted partial lists -> top-16, softmax, V-gather.
// ---------------------------------------------------------------------------
__device__ inline void ce_pair(float& v0, int& k0, float& v1, int& k1)
{
    // ascending by total order (val asc; on equal val, larger idx = "better")
    bool sw = (v0 > v1) || (v0 == v1 && k0 < k1);
    float tv = v0; int tk = k0;
    v0 = sw ? v1 : v0;  k0 = sw ? k1 : k0;
    v1 = sw ? tv : v1;  k1 = sw ? tk : k1;
}

__device__ inline void maxstep16(const float* av, const int* ak,
                                 const float* bv, const int* bk,
                                 float* ov, int* ok)
{
    #pragma unroll
    for (int i = 0; i < 16; ++i) {
        float bvv = bv[15 - i]; int bkk = bk[15 - i];
        bool ta = (av[i] > bvv) || (av[i] == bvv && ak[i] < bkk);
        ov[i] = ta ? av[i] : bvv;
        ok[i] = ta ? ak[i] : bkk;
    }
}

__device__ inline void bsort16(float* v, int* k)
{
    #pragma unroll
    for (int st = 8; st >= 1; st >>= 1) {
        #pragma unroll
        for (int i = 0; i < 16; ++i)
            if ((i & st) == 0) ce_pair(v[i], k[i], v[i + st], k[i + st]);
    }
}

__global__ __launch_bounds__(256) void topk_merge_kernel(
    const float2* __restrict__ P01, const float2* __restrict__ P23,
    const float* __restrict__ Vm, float* __restrict__ Om)
{
    int bid = blockIdx.x;            // (b*8 + h)*16 + qc
    int qc  = bid & 15;
    int h   = (bid >> 4) & 7;
    int b   = bid >> 7;
    int t   = threadIdx.x;
    int q   = qc * 256 + t;
    size_t qg = (size_t)b * NSEQ + q;

    float l0v[16], l1v[16], l2v[16], l3v[16];
    int   l0k[16], l1k[16], l2k[16], l3k[16];
    size_t base01 = (qg * NHEAD + h) * 2 * TOPK;
    #pragma unroll
    for (int i = 0; i < 16; ++i) {
        float2 p0 = P01[base01 + i];
        float2 p1 = P01[base01 + TOPK + i];
        float2 p2 = P23[base01 + i];
        float2 p3 = P23[base01 + TOPK + i];
        l0v[i] = p0.x; l0k[i] = __float_as_int(p0.y);
        l1v[i] = p1.x; l1k[i] = __float_as_int(p1.y);
        l2v[i] = p2.x; l2k[i] = __float_as_int(p2.y);
        l3v[i] = p3.x; l3k[i] = __float_as_int(p3.y);
    }

    float av[16], bv[16], fv[16];
    int   ak[16], bk[16], fk[16];
    maxstep16(l0v, l0k, l1v, l1k, av, ak);  bsort16(av, ak);
    maxstep16(l2v, l2k, l3v, l3k, bv, bk);  bsort16(bv, bk);
    maxstep16(av, ak, bv, bk, fv, fk);       // final top-16 multiset

    float m = fmaxf(av[15], bv[15]);
    float w[16];
    float wsum = 0.f;
    #pragma unroll
    for (int i = 0; i < 16; ++i) { w[i] = expf(fv[i] - m); wsum += w[i]; }
    float inv = 1.0f / wsum;
    const float* vp[16];
    #pragma unroll
    for (int i = 0; i < 16; ++i) {
        vp[i] = &Vm[((size_t)b * NSEQ + fk[i]) * DIMD + h * HD];
        w[i] *= inv;
    }
    float* op = Om + qg * DIMD + h * HD;
    #pragma unroll
    for (int d4 = 0; d4 < 16; ++d4) {
        float4 accv = make_float4(0.f, 0.f, 0.f, 0.f);
        #pragma unroll
        for (int i = 0; i < 16; ++i) {
            float4 vv = *(const float4*)&vp[i][d4 * 4];
            accv.x += w[i] * vv.x;
            accv.y += w[i] * vv.y;
            accv.z += w[i] * vv.z;
            accv.w += w[i] * vv.w;
        }
        *(float4*)&op[d4 * 4] = accv;
    }
}

// ---------------------------------------------------------------------------
extern "C" void kernel_launch(void* const* d_in, const int* in_sizes, int n_in,
                              void* d_out, int out_size, void* d_ws, size_t ws_size,
                              hipStream_t stream)
{
    (void)in_sizes; (void)n_in; (void)out_size; (void)ws_size;
    const float* x    = (const float*)d_in[0];
    const float* q_w  = (const float*)d_in[1];
    const float* q_b  = (const float*)d_in[2];
    const float* k_w  = (const float*)d_in[3];
    const float* k_b  = (const float*)d_in[4];
    const float* v_w  = (const float*)d_in[5];
    const float* v_b  = (const float*)d_in[6];
    const float* o_w  = (const float*)d_in[7];
    const float* o_b  = (const float*)d_in[8];
    const float* ln1g = (const float*)d_in[9];
    const float* ln1b = (const float*)d_in[10];
    const float* ln2g = (const float*)d_in[11];
    const float* ln2b = (const float*)d_in[12];
    const float* ff1w = (const float*)d_in[13];
    const float* ff1b = (const float*)d_in[14];
    const float* ff2w = (const float*)d_in[15];
    const float* ff2b = (const float*)d_in[16];
    float* out = (float*)d_out;
    float* ws  = (float*)d_ws;

    const size_t SZ = (size_t)8192 * DIMD;   // 4M floats = 16 MiB
    float*  Qb    = ws;                      // [8192 x 512]; later: attn out
    float*  Kb    = ws + SZ;
    float*  Vb    = ws + 2 * SZ;
    float2* P01   = (float2*)(ws + 3 * SZ);  // partials splits 0,1 (16 MiB)
    float2* P23   = (float2*)out;            // partials splits 2,3 (16 MiB, d_out free until O-proj)
    float2* stats = (float2*)(ws + 4 * SZ);  // 8192 float2
    float*  ffb   = ws;                      // [8192 x 2048], reuses all of ws

    dim3 g512(8, 128);    // Nn/64, M/64

    // LN1 stats, then Q/K/V projections with LN fused into the A-load.
    ln_stats_kernel<<<8192, 256, 0, stream>>>(x, stats);
    gemm_f32<<<g512, 256, 0, stream>>>(x, q_w, q_b, nullptr, Qb,
                                       512, 512, 0, stats, ln1g, ln1b);
    gemm_f32<<<g512, 256, 0, stream>>>(x, k_w, k_b, nullptr, Kb,
                                       512, 512, 0, stats, ln1g, ln1b);
    gemm_f32<<<g512, 256, 0, stream>>>(x, v_w, v_b, nullptr, Vb,
                                       512, 512, 0, stats, ln1g, ln1b);

    // Top-k: 4-way key split (occupancy 4 blocks/CU), then merge+softmax+
    // gather. Merge output overwrites Qb (Q dead after partial kernel).
    topk_partial_kernel<<<1024, 256, 0, stream>>>(Qb, Kb, P01, P23);
    topk_merge_kernel<<<256, 256, 0, stream>>>(P01, P23, Vb, Qb);

    // x2 = x + attnOut @ o_w + o_b   -> d_out (overwrites partial scratch)
    gemm_f32<<<g512, 256, 0, stream>>>(Qb, o_w, o_b, x, out,
                                       512, 512, 0, nullptr, nullptr, nullptr);

    // LN2 stats from x2, FFN with LN fused; ff1 -> ffb (gelu), then
    // out = x2 + ffb @ ff2_w + ff2_b (in-place residual on d_out).
    ln_stats_kernel<<<8192, 256, 0, stream>>>(out, stats);
    gemm_f32<<<dim3(32, 128), 256, 0, stream>>>(out, ff1w, ff1b, nullptr, ffb,
                                                512, 2048, 1, stats, ln2g, ln2b);
    gemm_f32<<<g512, 256, 0, stream>>>(ffb, ff2w, ff2b, out, out,
                                       2048, 512, 0, nullptr, nullptr, nullptr);
}

// Round 3
// 2091.896 us; speedup vs baseline: 2.7757x; 1.1397x over previous
//
#include <hip/hip_runtime.h>
#include <math.h>

#define DIMD 512
#define NSEQ 4096
#define NHEAD 8
#define HD 64
#define TOPK 16
#define NSPLIT 4
#define CHUNK (NSEQ / NSPLIT)   // 1024 keys per split

// ---------------------------------------------------------------------------
// Per-row LayerNorm stats: mean and 1/sqrt(var+eps). One block per row.
// ---------------------------------------------------------------------------
__global__ __launch_bounds__(256) void ln_stats_kernel(
    const float* __restrict__ X, float2* __restrict__ S)
{
    int r = blockIdx.x;
    int t = threadIdx.x;
    const float* xr = X + (size_t)r * DIMD;
    float a = xr[t], b = xr[t + 256];
    float s = a + b;
    float sq = a * a + b * b;
    #pragma unroll
    for (int off = 32; off > 0; off >>= 1) {
        s  += __shfl_down(s, off, 64);
        sq += __shfl_down(sq, off, 64);
    }
    __shared__ float red[8];
    int wv = t >> 6, ln = t & 63;
    if (ln == 0) { red[wv] = s; red[wv + 4] = sq; }
    __syncthreads();
    if (t == 0) {
        float st  = red[0] + red[1] + red[2] + red[3];
        float sqt = red[4] + red[5] + red[6] + red[7];
        float mean = st * (1.0f / DIMD);
        float var  = sqt * (1.0f / DIMD) - mean * mean;
        float inv  = 1.0f / sqrtf(var + 1e-5f);
        S[r] = make_float2(mean, inv);
    }
}

// ---------------------------------------------------------------------------
// fp32 GEMM: C[M x Nn] = act(LN(A) @ W + bias) (+ R)
// Block: 256 threads, tile 64x64, BK=32; each thread computes 4x4.
// ---------------------------------------------------------------------------
__global__ __launch_bounds__(256) void gemm_f32(
    const float* __restrict__ A, const float* __restrict__ W,
    const float* __restrict__ bias, const float* __restrict__ R,
    float* __restrict__ C, int Kd, int Nn, int gelu,
    const float2* __restrict__ lnstats,
    const float* __restrict__ lng, const float* __restrict__ lnb)
{
    __shared__ float As[32][64];   // transposed: As[k][m]
    __shared__ float Ws[32][64];   // Ws[k][n]
    int n0 = blockIdx.x * 64;
    int m0 = blockIdx.y * 64;
    int t  = threadIdx.x;
    int tr = t >> 4, tc = t & 15;
    float acc[4][4] = {};

    for (int k0 = 0; k0 < Kd; k0 += 32) {
        #pragma unroll
        for (int qq = 0; qq < 2; ++qq) {
            int idx = t * 2 + qq;              // 0..511
            int r   = idx >> 3;                // 0..63
            int c4  = idx & 7;                 // 0..7
            float4 av = *(const float4*)&A[(size_t)(m0 + r) * Kd + k0 + c4 * 4];
            if (lnstats) {
                float2 st = lnstats[m0 + r];
                float4 gv = *(const float4*)&lng[k0 + c4 * 4];
                float4 bv = *(const float4*)&lnb[k0 + c4 * 4];
                av.x = (av.x - st.x) * st.y * gv.x + bv.x;
                av.y = (av.y - st.x) * st.y * gv.y + bv.y;
                av.z = (av.z - st.x) * st.y * gv.z + bv.z;
                av.w = (av.w - st.x) * st.y * gv.w + bv.w;
            }
            As[c4 * 4 + 0][r] = av.x;
            As[c4 * 4 + 1][r] = av.y;
            As[c4 * 4 + 2][r] = av.z;
            As[c4 * 4 + 3][r] = av.w;
            int kr  = idx >> 4;                // 0..31
            int nc4 = idx & 15;                // 0..15
            *(float4*)&Ws[kr][nc4 * 4] =
                *(const float4*)&W[(size_t)(k0 + kr) * Nn + n0 + nc4 * 4];
        }
        __syncthreads();
        #pragma unroll
        for (int kk = 0; kk < 32; ++kk) {
            float4 a = *(const float4*)&As[kk][tr * 4];
            float4 b = *(const float4*)&Ws[kk][tc * 4];
            acc[0][0] += a.x * b.x; acc[0][1] += a.x * b.y;
            acc[0][2] += a.x * b.z; acc[0][3] += a.x * b.w;
            acc[1][0] += a.y * b.x; acc[1][1] += a.y * b.y;
            acc[1][2] += a.y * b.z; acc[1][3] += a.y * b.w;
            acc[2][0] += a.z * b.x; acc[2][1] += a.z * b.y;
            acc[2][2] += a.z * b.z; acc[2][3] += a.z * b.w;
            acc[3][0] += a.w * b.x; acc[3][1] += a.w * b.y;
            acc[3][2] += a.w * b.z; acc[3][3] += a.w * b.w;
        }
        __syncthreads();
    }

    float4 bb = *(const float4*)&bias[n0 + tc * 4];
    #pragma unroll
    for (int i = 0; i < 4; ++i) {
        int row = m0 + tr * 4 + i;
        float4 o;
        o.x = acc[i][0] + bb.x;
        o.y = acc[i][1] + bb.y;
        o.z = acc[i][2] + bb.z;
        o.w = acc[i][3] + bb.w;
        if (gelu) {
            o.x = 0.5f * o.x * (1.0f + erff(o.x * 0.70710678118654752f));
            o.y = 0.5f * o.y * (1.0f + erff(o.y * 0.70710678118654752f));
            o.z = 0.5f * o.z * (1.0f + erff(o.z * 0.70710678118654752f));
            o.w = 0.5f * o.w * (1.0f + erff(o.w * 0.70710678118654752f));
        }
        if (R) {
            float4 rv = *(const float4*)&R[(size_t)row * Nn + n0 + tc * 4];
            o.x += rv.x; o.y += rv.y; o.z += rv.z; o.w += rv.w;
        }
        *(float4*)&C[(size_t)row * Nn + n0 + tc * 4] = o;
    }
}

// ---------------------------------------------------------------------------
// Partial top-16 over one key chunk. 1 thread = 1 query, streams CHUNK keys.
// __launch_bounds__(256,3): VGPR budget 170 — fits the ~140 live regs
// (qv=64 + list=32 + temps) WITHOUT AGPR-copy traffic (round-2 lesson:
// (256,4) forced VGPR=64 and the compiler emitted v_accvgpr_read/write
// around every array access — 3x VALU bloat).
// ---------------------------------------------------------------------------
__global__ __launch_bounds__(256, 3) void topk_partial_kernel(
    const float* __restrict__ Qm, const float* __restrict__ Km,
    float2* __restrict__ P01, float2* __restrict__ P23)
{
    int bid = blockIdx.x;
    int qc  = bid & 15;
    int s   = (bid >> 4) & 3;
    int h   = (bid >> 6) & 7;
    int b   = bid >> 9;
    int t   = threadIdx.x;
    int q   = qc * 256 + t;
    size_t qg   = (size_t)b * NSEQ + q;
    size_t qoff = qg * DIMD + h * HD;

    float4 qv[16];
    #pragma unroll
    for (int i = 0; i < 16; ++i) qv[i] = *(const float4*)&Qm[qoff + i * 4];

    float vals[TOPK];
    int   idxs[TOPK];
    #pragma unroll
    for (int i = 0; i < TOPK; ++i) { vals[i] = -INFINITY; idxs[i] = 0; }

    __shared__ float4 Ks[64 * 16];    // 64 keys x 64 dims
    size_t kbase = ((size_t)b * NSEQ) * DIMD + h * HD;
    int k0base = s * CHUNK;

    for (int t0 = 0; t0 < CHUNK; t0 += 64) {
        #pragma unroll
        for (int qq = 0; qq < 4; ++qq) {
            int idx = t + 256 * qq;          // 0..1023
            int r   = idx >> 4;              // 0..63
            int c4  = idx & 15;              // 0..15
            Ks[r * 16 + c4] = *(const float4*)
                &Km[kbase + (size_t)(k0base + t0 + r) * DIMD + c4 * 4];
        }
        __syncthreads();
        for (int j = 0; j < 64; ++j) {
            float a0 = 0.f, a1 = 0.f, a2 = 0.f, a3 = 0.f;
            #pragma unroll
            for (int d4 = 0; d4 < 16; ++d4) {
                float4 kv = Ks[j * 16 + d4];
                a0 += qv[d4].x * kv.x;
                a1 += qv[d4].y * kv.y;
                a2 += qv[d4].z * kv.z;
                a3 += qv[d4].w * kv.w;
            }
            float sc = ((a0 + a1) + (a2 + a3)) * 0.125f;
            // sorted-ascending insert; strict compares => lower index wins
            // ties (matches lax.top_k). Bools computed once, reused for
            // vals and idxs.
            if (vals[0] < sc) {
                int kidx = k0base + t0 + j;
                bool gt[TOPK];
                #pragma unroll
                for (int i = 1; i < TOPK; ++i) gt[i] = vals[i] < sc;
                #pragma unroll
                for (int i = 0; i < TOPK - 1; ++i) {
                    vals[i] = gt[i + 1] ? vals[i + 1] : ((i == 0 || gt[i]) ? sc : vals[i]);
                    idxs[i] = gt[i + 1] ? idxs[i + 1] : ((i == 0 || gt[i]) ? kidx : idxs[i]);
                }
                vals[TOPK - 1] = gt[TOPK - 1] ? sc : vals[TOPK - 1];
                idxs[TOPK - 1] = gt[TOPK - 1] ? kidx : idxs[TOPK - 1];
            }
        }
        __syncthreads();
    }

    float2* P = (s < 2) ? P01 : P23;
    size_t base = (((qg * NHEAD + h) * 2) + (s & 1)) * TOPK;
    #pragma unroll
    for (int i = 0; i < TOPK; ++i)
        P[base + i] = make_float2(vals[i], __int_as_float(idxs[i]));
}

// ---------------------------------------------------------------------------
// Merge 4 sorted partial lists -> top-16, softmax, V-gather.
// Grid 512: blocks come in pairs; each pair-half gathers half the head dims
// (merge math redundant, gathers split for 2x latency hiding).
// ---------------------------------------------------------------------------
__device__ inline void ce_pair(float& v0, int& k0, float& v1, int& k1)
{
    bool sw = (v0 > v1) || (v0 == v1 && k0 < k1);
    float tv = v0; int tk = k0;
    v0 = sw ? v1 : v0;  k0 = sw ? k1 : k0;
    v1 = sw ? tv : v1;  k1 = sw ? tk : k1;
}

__device__ inline void maxstep16(const float* av, const int* ak,
                                 const float* bv, const int* bk,
                                 float* ov, int* ok)
{
    #pragma unroll
    for (int i = 0; i < 16; ++i) {
        float bvv = bv[15 - i]; int bkk = bk[15 - i];
        bool ta = (av[i] > bvv) || (av[i] == bvv && ak[i] < bkk);
        ov[i] = ta ? av[i] : bvv;
        ok[i] = ta ? ak[i] : bkk;
    }
}

__device__ inline void bsort16(float* v, int* k)
{
    #pragma unroll
    for (int st = 8; st >= 1; st >>= 1) {
        #pragma unroll
        for (int i = 0; i < 16; ++i)
            if ((i & st) == 0) ce_pair(v[i], k[i], v[i + st], k[i + st]);
    }
}

__global__ __launch_bounds__(256) void topk_merge_kernel(
    const float2* __restrict__ P01, const float2* __restrict__ P23,
    const float* __restrict__ Vm, float* __restrict__ Om)
{
    int bid  = blockIdx.x;           // ((b*8 + h)*16 + qc)*2 + half
    int half = bid & 1;
    int ob   = bid >> 1;
    int qc   = ob & 15;
    int h    = (ob >> 4) & 7;
    int b    = ob >> 7;
    int t    = threadIdx.x;
    int q    = qc * 256 + t;
    size_t qg = (size_t)b * NSEQ + q;

    float l0v[16], l1v[16], l2v[16], l3v[16];
    int   l0k[16], l1k[16], l2k[16], l3k[16];
    size_t base01 = (qg * NHEAD + h) * 2 * TOPK;
    #pragma unroll
    for (int i = 0; i < 16; ++i) {
        float2 p0 = P01[base01 + i];
        float2 p1 = P01[base01 + TOPK + i];
        float2 p2 = P23[base01 + i];
        float2 p3 = P23[base01 + TOPK + i];
        l0v[i] = p0.x; l0k[i] = __float_as_int(p0.y);
        l1v[i] = p1.x; l1k[i] = __float_as_int(p1.y);
        l2v[i] = p2.x; l2k[i] = __float_as_int(p2.y);
        l3v[i] = p3.x; l3k[i] = __float_as_int(p3.y);
    }

    float av[16], bv[16], fv[16];
    int   ak[16], bk[16], fk[16];
    maxstep16(l0v, l0k, l1v, l1k, av, ak);  bsort16(av, ak);
    maxstep16(l2v, l2k, l3v, l3k, bv, bk);  bsort16(bv, bk);
    maxstep16(av, ak, bv, bk, fv, fk);       // final top-16 multiset

    float m = fmaxf(av[15], bv[15]);
    float w[16];
    float wsum = 0.f;
    #pragma unroll
    for (int i = 0; i < 16; ++i) { w[i] = expf(fv[i] - m); wsum += w[i]; }
    float inv = 1.0f / wsum;
    const float* vp[16];
    #pragma unroll
    for (int i = 0; i < 16; ++i) {
        vp[i] = &Vm[((size_t)b * NSEQ + fk[i]) * DIMD + h * HD + half * 32];
        w[i] *= inv;
    }
    float* op = Om + qg * DIMD + h * HD + half * 32;
    #pragma unroll
    for (int d4 = 0; d4 < 8; ++d4) {
        float4 accv = make_float4(0.f, 0.f, 0.f, 0.f);
        #pragma unroll
        for (int i = 0; i < 16; ++i) {
            float4 vv = *(const float4*)&vp[i][d4 * 4];
            accv.x += w[i] * vv.x;
            accv.y += w[i] * vv.y;
            accv.z += w[i] * vv.z;
            accv.w += w[i] * vv.w;
        }
        *(float4*)&op[d4 * 4] = accv;
    }
}

// ---------------------------------------------------------------------------
extern "C" void kernel_launch(void* const* d_in, const int* in_sizes, int n_in,
                              void* d_out, int out_size, void* d_ws, size_t ws_size,
                              hipStream_t stream)
{
    (void)in_sizes; (void)n_in; (void)out_size; (void)ws_size;
    const float* x    = (const float*)d_in[0];
    const float* q_w  = (const float*)d_in[1];
    const float* q_b  = (const float*)d_in[2];
    const float* k_w  = (const float*)d_in[3];
    const float* k_b  = (const float*)d_in[4];
    const float* v_w  = (const float*)d_in[5];
    const float* v_b  = (const float*)d_in[6];
    const float* o_w  = (const float*)d_in[7];
    const float* o_b  = (const float*)d_in[8];
    const float* ln1g = (const float*)d_in[9];
    const float* ln1b = (const float*)d_in[10];
    const float* ln2g = (const float*)d_in[11];
    const float* ln2b = (const float*)d_in[12];
    const float* ff1w = (const float*)d_in[13];
    const float* ff1b = (const float*)d_in[14];
    const float* ff2w = (const float*)d_in[15];
    const float* ff2b = (const float*)d_in[16];
    float* out = (float*)d_out;
    float* ws  = (float*)d_ws;

    const size_t SZ = (size_t)8192 * DIMD;   // 4M floats = 16 MiB
    float*  Qb    = ws;                      // [8192 x 512]; later: attn out
    float*  Kb    = ws + SZ;
    float*  Vb    = ws + 2 * SZ;
    float2* P01   = (float2*)(ws + 3 * SZ);  // partials splits 0,1 (16 MiB)
    float2* P23   = (float2*)out;            // partials splits 2,3 (d_out free until O-proj)
    float2* stats = (float2*)(ws + 4 * SZ);  // 8192 float2
    float*  ffb   = ws;                      // [8192 x 2048], reuses all of ws

    dim3 g512(8, 128);    // Nn/64, M/64

    // LN1 stats, then Q/K/V projections with LN fused into the A-load.
    ln_stats_kernel<<<8192, 256, 0, stream>>>(x, stats);
    gemm_f32<<<g512, 256, 0, stream>>>(x, q_w, q_b, nullptr, Qb,
                                       512, 512, 0, stats, ln1g, ln1b);
    gemm_f32<<<g512, 256, 0, stream>>>(x, k_w, k_b, nullptr, Kb,
                                       512, 512, 0, stats, ln1g, ln1b);
    gemm_f32<<<g512, 256, 0, stream>>>(x, v_w, v_b, nullptr, Vb,
                                       512, 512, 0, stats, ln1g, ln1b);

    // Top-k: 4-way key split, then merge+softmax+gather (dims split 2-way).
    topk_partial_kernel<<<1024, 256, 0, stream>>>(Qb, Kb, P01, P23);
    topk_merge_kernel<<<512, 256, 0, stream>>>(P01, P23, Vb, Qb);

    // x2 = x + attnOut @ o_w + o_b   -> d_out (overwrites partial scratch)
    gemm_f32<<<g512, 256, 0, stream>>>(Qb, o_w, o_b, x, out,
                                       512, 512, 0, nullptr, nullptr, nullptr);

    // LN2 stats from x2, FFN with LN fused; ff1 -> ffb (gelu), then
    // out = x2 + ffb @ ff2_w + ff2_b (in-place residual on d_out).
    ln_stats_kernel<<<8192, 256, 0, stream>>>(out, stats);
    gemm_f32<<<dim3(32, 128), 256, 0, stream>>>(out, ff1w, ff1b, nullptr, ffb,
                                                512, 2048, 1, stats, ln2g, ln2b);
    gemm_f32<<<g512, 256, 0, stream>>>(ffb, ff2w, ff2b, out, out,
                                       2048, 512, 0, nullptr, nullptr, nullptr);
}

// Round 4
// 2090.693 us; speedup vs baseline: 2.7773x; 1.0006x over previous
//
#include <hip/hip_runtime.h>
#include <math.h>

#define DIMD 512
#define NSEQ 4096
#define NHEAD 8
#define HD 64
#define TOPK 16

// ---------------------------------------------------------------------------
// Per-row LayerNorm stats: mean and 1/sqrt(var+eps). One block per row.
// ---------------------------------------------------------------------------
__global__ __launch_bounds__(256) void ln_stats_kernel(
    const float* __restrict__ X, float2* __restrict__ S)
{
    int r = blockIdx.x;
    int t = threadIdx.x;
    const float* xr = X + (size_t)r * DIMD;
    float a = xr[t], b = xr[t + 256];
    float s = a + b;
    float sq = a * a + b * b;
    #pragma unroll
    for (int off = 32; off > 0; off >>= 1) {
        s  += __shfl_down(s, off, 64);
        sq += __shfl_down(sq, off, 64);
    }
    __shared__ float red[8];
    int wv = t >> 6, ln = t & 63;
    if (ln == 0) { red[wv] = s; red[wv + 4] = sq; }
    __syncthreads();
    if (t == 0) {
        float st  = red[0] + red[1] + red[2] + red[3];
        float sqt = red[4] + red[5] + red[6] + red[7];
        float mean = st * (1.0f / DIMD);
        float var  = sqt * (1.0f / DIMD) - mean * mean;
        float inv  = 1.0f / sqrtf(var + 1e-5f);
        S[r] = make_float2(mean, inv);
    }
}

// ---------------------------------------------------------------------------
// fp32 GEMM: C[M x Nn] = act(LN(A) @ W + bias) (+ R)
// Block: 256 threads, tile 64x64, BK=32; each thread computes 4x4.
// ---------------------------------------------------------------------------
__global__ __launch_bounds__(256) void gemm_f32(
    const float* __restrict__ A, const float* __restrict__ W,
    const float* __restrict__ bias, const float* __restrict__ R,
    float* __restrict__ C, int Kd, int Nn, int gelu,
    const float2* __restrict__ lnstats,
    const float* __restrict__ lng, const float* __restrict__ lnb)
{
    __shared__ float As[32][64];   // transposed: As[k][m]
    __shared__ float Ws[32][64];   // Ws[k][n]
    int n0 = blockIdx.x * 64;
    int m0 = blockIdx.y * 64;
    int t  = threadIdx.x;
    int tr = t >> 4, tc = t & 15;
    float acc[4][4] = {};

    for (int k0 = 0; k0 < Kd; k0 += 32) {
        #pragma unroll
        for (int qq = 0; qq < 2; ++qq) {
            int idx = t * 2 + qq;              // 0..511
            int r   = idx >> 3;                // 0..63
            int c4  = idx & 7;                 // 0..7
            float4 av = *(const float4*)&A[(size_t)(m0 + r) * Kd + k0 + c4 * 4];
            if (lnstats) {
                float2 st = lnstats[m0 + r];
                float4 gv = *(const float4*)&lng[k0 + c4 * 4];
                float4 bv = *(const float4*)&lnb[k0 + c4 * 4];
                av.x = (av.x - st.x) * st.y * gv.x + bv.x;
                av.y = (av.y - st.x) * st.y * gv.y + bv.y;
                av.z = (av.z - st.x) * st.y * gv.z + bv.z;
                av.w = (av.w - st.x) * st.y * gv.w + bv.w;
            }
            As[c4 * 4 + 0][r] = av.x;
            As[c4 * 4 + 1][r] = av.y;
            As[c4 * 4 + 2][r] = av.z;
            As[c4 * 4 + 3][r] = av.w;
            int kr  = idx >> 4;                // 0..31
            int nc4 = idx & 15;                // 0..15
            *(float4*)&Ws[kr][nc4 * 4] =
                *(const float4*)&W[(size_t)(k0 + kr) * Nn + n0 + nc4 * 4];
        }
        __syncthreads();
        #pragma unroll
        for (int kk = 0; kk < 32; ++kk) {
            float4 a = *(const float4*)&As[kk][tr * 4];
            float4 b = *(const float4*)&Ws[kk][tc * 4];
            acc[0][0] += a.x * b.x; acc[0][1] += a.x * b.y;
            acc[0][2] += a.x * b.z; acc[0][3] += a.x * b.w;
            acc[1][0] += a.y * b.x; acc[1][1] += a.y * b.y;
            acc[1][2] += a.y * b.z; acc[1][3] += a.y * b.w;
            acc[2][0] += a.z * b.x; acc[2][1] += a.z * b.y;
            acc[2][2] += a.z * b.z; acc[2][3] += a.z * b.w;
            acc[3][0] += a.w * b.x; acc[3][1] += a.w * b.y;
            acc[3][2] += a.w * b.z; acc[3][3] += a.w * b.w;
        }
        __syncthreads();
    }

    float4 bb = *(const float4*)&bias[n0 + tc * 4];
    #pragma unroll
    for (int i = 0; i < 4; ++i) {
        int row = m0 + tr * 4 + i;
        float4 o;
        o.x = acc[i][0] + bb.x;
        o.y = acc[i][1] + bb.y;
        o.z = acc[i][2] + bb.z;
        o.w = acc[i][3] + bb.w;
        if (gelu) {
            o.x = 0.5f * o.x * (1.0f + erff(o.x * 0.70710678118654752f));
            o.y = 0.5f * o.y * (1.0f + erff(o.y * 0.70710678118654752f));
            o.z = 0.5f * o.z * (1.0f + erff(o.z * 0.70710678118654752f));
            o.w = 0.5f * o.w * (1.0f + erff(o.w * 0.70710678118654752f));
        }
        if (R) {
            float4 rv = *(const float4*)&R[(size_t)row * Nn + n0 + tc * 4];
            o.x += rv.x; o.y += rv.y; o.z += rv.z; o.w += rv.w;
        }
        *(float4*)&C[(size_t)row * Nn + n0 + tc * 4] = o;
    }
}

// ---------------------------------------------------------------------------
// Fused top-16 attention: scores + selection + softmax + V-gather.
// Block = 512 threads (8 waves) = 64 queries of one (b,h).
// Wave layout: lane = key (K row in 16 float4 regs, loaded once per tile,
// reused by 8 queries). q-vectors are wave-uniform -> SGPRs. Top-16 lists
// are lane-distributed: 16 slots (sorted ascending) in 16 lanes; 2 register
// sets x 4 lane-groups = 8 queries/wave. Candidates via ballot(sc > theta)
// (cheap no-op when none), inserted by a uniform scalar loop.
// Selection arithmetic is order-identical fp32 vs previous rounds.
// ---------------------------------------------------------------------------
#define INSERT_SLOT(SLOTV, SLOTI)                                        \
    {                                                                    \
        unsigned long long lt = __ballot(SLOTV < scb);                   \
        int cnt = __popcll((lt >> (gg * 16)) & 0xFFFFull);               \
        if (cnt) {                                                       \
            float shv = __shfl(SLOTV, (lane + 1) & 63);                  \
            int   shi = __shfl(SLOTI, (lane + 1) & 63);                  \
            bool put = ing && (s == cnt - 1);                            \
            bool shf = ing && (s < cnt - 1);                             \
            SLOTV = put ? scb : (shf ? shv : SLOTV);                     \
            SLOTI = put ? idxb : (shf ? shi : SLOTI);                    \
        }                                                                \
    }

__global__ __launch_bounds__(512, 2) void topk_attn_fused(
    const float* __restrict__ Qm, const float* __restrict__ Km,
    const float* __restrict__ Vm, float* __restrict__ Om)
{
    __shared__ float4 Ks4[64 * 16];   // 64 keys x 16 float4, XOR-swizzled

    int bid = blockIdx.x;
    int bh  = bid >> 6;               // 0..15
    int qt  = bid & 63;               // query tile within (b,h)
    int b   = bh >> 3, h = bh & 7;
    int qbase = qt * 64;
    int tid  = threadIdx.x;
    int wid  = __builtin_amdgcn_readfirstlane(tid >> 6);  // wave 0..7
    int lane = tid & 63;
    int grp  = lane >> 4;             // slot group 0..3
    int s    = lane & 15;             // slot index within group

    size_t kbase = ((size_t)b * NSEQ) * DIMD + h * HD;
    const float* qrow0 = Qm + ((size_t)(b * NSEQ + qbase + wid * 8)) * DIMD + h * HD;

    float slotvA = -INFINITY, slotvB = -INFINITY;
    int   slotiA = 0,         slotiB = 0;

    for (int t0 = 0; t0 < NSEQ; t0 += 64) {
        __syncthreads();
        #pragma unroll
        for (int qq = 0; qq < 2; ++qq) {
            int idx = tid * 2 + qq;          // 0..1023
            int r   = idx >> 4;              // key row 0..63
            int c4  = idx & 15;
            Ks4[r * 16 + (c4 ^ (r & 15))] =
                *(const float4*)&Km[kbase + (size_t)(t0 + r) * DIMD + c4 * 4];
        }
        __syncthreads();

        float4 kr[16];                       // this lane's key row
        #pragma unroll
        for (int d4 = 0; d4 < 16; ++d4)
            kr[d4] = Ks4[lane * 16 + (d4 ^ (lane & 15))];

        #pragma unroll
        for (int g = 0; g < 8; ++g) {
            const float* qrow = qrow0 + (size_t)g * DIMD;  // wave-uniform
            float a0 = 0.f, a1 = 0.f, a2 = 0.f, a3 = 0.f;
            #pragma unroll
            for (int d4 = 0; d4 < 16; ++d4) {
                float4 qv = *(const float4*)(qrow + d4 * 4);
                a0 = fmaf(qv.x, kr[d4].x, a0);
                a1 = fmaf(qv.y, kr[d4].y, a1);
                a2 = fmaf(qv.z, kr[d4].z, a2);
                a3 = fmaf(qv.w, kr[d4].w, a3);
            }
            float sc = ((a0 + a1) + (a2 + a3)) * 0.125f;

            int gg = g & 3;
            bool ing = (grp == gg);
            float theta = __shfl((g < 4) ? slotvA : slotvB, gg * 16);
            unsigned long long cand = __ballot(sc > theta);
            while (cand) {                    // uniform scalar loop
                int src = __ffsll(cand) - 1;
                cand &= cand - 1;
                float scb  = __shfl(sc, src); // candidates in ascending key
                int   idxb = t0 + src;        // order -> stable ties
                if (g < 4) INSERT_SLOT(slotvA, slotiA)
                else       INSERT_SLOT(slotvB, slotiB)
            }
        }
    }

    // ---- softmax + V-gather, set A (queries g=0..3) then set B (4..7) ----
    #pragma unroll
    for (int set = 0; set < 2; ++set) {
        float slotv = set ? slotvB : slotvA;
        int   sloti = set ? slotiB : slotiA;
        float mx = __shfl(slotv, (lane & 48) + 15);   // per-group max
        float w  = expf(slotv - mx);
        float ssum = w;
        #pragma unroll
        for (int off = 1; off < 16; off <<= 1) ssum += __shfl_xor(ssum, off);
        float wn = w * (1.0f / ssum);

        #pragma unroll
        for (int gg2 = 0; gg2 < 4; ++gg2) {
            float acc = 0.f;
            #pragma unroll
            for (int i = 15; i >= 0; --i) {   // descending = ref's topk order
                float wi = __shfl(wn, gg2 * 16 + i);
                int   ki = __shfl(sloti, gg2 * 16 + i);
                acc = fmaf(wi, Vm[((size_t)(b * NSEQ + ki)) * DIMD + h * HD + lane], acc);
            }
            int qn = qbase + wid * 8 + set * 4 + gg2;
            Om[((size_t)(b * NSEQ + qn)) * DIMD + h * HD + lane] = acc;
        }
    }
}

// ---------------------------------------------------------------------------
extern "C" void kernel_launch(void* const* d_in, const int* in_sizes, int n_in,
                              void* d_out, int out_size, void* d_ws, size_t ws_size,
                              hipStream_t stream)
{
    (void)in_sizes; (void)n_in; (void)out_size; (void)ws_size;
    const float* x    = (const float*)d_in[0];
    const float* q_w  = (const float*)d_in[1];
    const float* q_b  = (const float*)d_in[2];
    const float* k_w  = (const float*)d_in[3];
    const float* k_b  = (const float*)d_in[4];
    const float* v_w  = (const float*)d_in[5];
    const float* v_b  = (const float*)d_in[6];
    const float* o_w  = (const float*)d_in[7];
    const float* o_b  = (const float*)d_in[8];
    const float* ln1g = (const float*)d_in[9];
    const float* ln1b = (const float*)d_in[10];
    const float* ln2g = (const float*)d_in[11];
    const float* ln2b = (const float*)d_in[12];
    const float* ff1w = (const float*)d_in[13];
    const float* ff1b = (const float*)d_in[14];
    const float* ff2w = (const float*)d_in[15];
    const float* ff2b = (const float*)d_in[16];
    float* out = (float*)d_out;
    float* ws  = (float*)d_ws;

    const size_t SZ = (size_t)8192 * DIMD;   // 4M floats = 16 MiB
    float*  Qb      = ws;                    // [8192 x 512]
    float*  Kb      = ws + SZ;
    float*  Vb      = ws + 2 * SZ;
    float*  attnOut = ws + 3 * SZ;           // [8192 x 512]
    float2* stats   = (float2*)(ws + 4 * SZ);
    float*  ffb     = ws;                    // [8192 x 2048], reuses ws

    dim3 g512(8, 128);    // Nn/64, M/64

    // LN1 stats, then Q/K/V projections with LN fused into the A-load.
    ln_stats_kernel<<<8192, 256, 0, stream>>>(x, stats);
    gemm_f32<<<g512, 256, 0, stream>>>(x, q_w, q_b, nullptr, Qb,
                                       512, 512, 0, stats, ln1g, ln1b);
    gemm_f32<<<g512, 256, 0, stream>>>(x, k_w, k_b, nullptr, Kb,
                                       512, 512, 0, stats, ln1g, ln1b);
    gemm_f32<<<g512, 256, 0, stream>>>(x, v_w, v_b, nullptr, Vb,
                                       512, 512, 0, stats, ln1g, ln1b);

    // Fused top-16 attention (scores + select + softmax + gather).
    topk_attn_fused<<<1024, 512, 0, stream>>>(Qb, Kb, Vb, attnOut);

    // x2 = x + attnOut @ o_w + o_b   -> d_out
    gemm_f32<<<g512, 256, 0, stream>>>(attnOut, o_w, o_b, x, out,
                                       512, 512, 0, nullptr, nullptr, nullptr);

    // LN2 stats from x2, FFN with LN fused; ff1 -> ffb (gelu), then
    // out = x2 + ffb @ ff2_w + ff2_b (in-place residual on d_out).
    ln_stats_kernel<<<8192, 256, 0, stream>>>(out, stats);
    gemm_f32<<<dim3(32, 128), 256, 0, stream>>>(out, ff1w, ff1b, nullptr, ffb,
                                                512, 2048, 1, stats, ln2g, ln2b);
    gemm_f32<<<g512, 256, 0, stream>>>(ffb, ff2w, ff2b, out, out,
                                       2048, 512, 0, nullptr, nullptr, nullptr);
}

// Round 5
// 1966.822 us; speedup vs baseline: 2.9522x; 1.0630x over previous
//
#include <hip/hip_runtime.h>
#include <math.h>

#define DIMD 512
#define NSEQ 4096
#define NHEAD 8
#define HD 64
#define TOPK 16

// ---------------------------------------------------------------------------
// Per-row LayerNorm stats: mean and 1/sqrt(var+eps). One block per row.
// ---------------------------------------------------------------------------
__global__ __launch_bounds__(256) void ln_stats_kernel(
    const float* __restrict__ X, float2* __restrict__ S)
{
    int r = blockIdx.x;
    int t = threadIdx.x;
    const float* xr = X + (size_t)r * DIMD;
    float a = xr[t], b = xr[t + 256];
    float s = a + b;
    float sq = a * a + b * b;
    #pragma unroll
    for (int off = 32; off > 0; off >>= 1) {
        s  += __shfl_down(s, off, 64);
        sq += __shfl_down(sq, off, 64);
    }
    __shared__ float red[8];
    int wv = t >> 6, ln = t & 63;
    if (ln == 0) { red[wv] = s; red[wv + 4] = sq; }
    __syncthreads();
    if (t == 0) {
        float st  = red[0] + red[1] + red[2] + red[3];
        float sqt = red[4] + red[5] + red[6] + red[7];
        float mean = st * (1.0f / DIMD);
        float var  = sqt * (1.0f / DIMD) - mean * mean;
        float inv  = 1.0f / sqrtf(var + 1e-5f);
        S[r] = make_float2(mean, inv);
    }
}

// ---------------------------------------------------------------------------
// fp32 GEMM: C[M x Nn] = act(LN(A) @ W + bias) (+ R)
// Block: 256 threads, tile 64x64, BK=32; each thread computes 4x4.
// ---------------------------------------------------------------------------
__global__ __launch_bounds__(256) void gemm_f32(
    const float* __restrict__ A, const float* __restrict__ W,
    const float* __restrict__ bias, const float* __restrict__ R,
    float* __restrict__ C, int Kd, int Nn, int gelu,
    const float2* __restrict__ lnstats,
    const float* __restrict__ lng, const float* __restrict__ lnb)
{
    __shared__ float As[32][64];   // transposed: As[k][m]
    __shared__ float Ws[32][64];   // Ws[k][n]
    int n0 = blockIdx.x * 64;
    int m0 = blockIdx.y * 64;
    int t  = threadIdx.x;
    int tr = t >> 4, tc = t & 15;
    float acc[4][4] = {};

    for (int k0 = 0; k0 < Kd; k0 += 32) {
        #pragma unroll
        for (int qq = 0; qq < 2; ++qq) {
            int idx = t * 2 + qq;              // 0..511
            int r   = idx >> 3;                // 0..63
            int c4  = idx & 7;                 // 0..7
            float4 av = *(const float4*)&A[(size_t)(m0 + r) * Kd + k0 + c4 * 4];
            if (lnstats) {
                float2 st = lnstats[m0 + r];
                float4 gv = *(const float4*)&lng[k0 + c4 * 4];
                float4 bv = *(const float4*)&lnb[k0 + c4 * 4];
                av.x = (av.x - st.x) * st.y * gv.x + bv.x;
                av.y = (av.y - st.x) * st.y * gv.y + bv.y;
                av.z = (av.z - st.x) * st.y * gv.z + bv.z;
                av.w = (av.w - st.x) * st.y * gv.w + bv.w;
            }
            As[c4 * 4 + 0][r] = av.x;
            As[c4 * 4 + 1][r] = av.y;
            As[c4 * 4 + 2][r] = av.z;
            As[c4 * 4 + 3][r] = av.w;
            int kr  = idx >> 4;                // 0..31
            int nc4 = idx & 15;                // 0..15
            *(float4*)&Ws[kr][nc4 * 4] =
                *(const float4*)&W[(size_t)(k0 + kr) * Nn + n0 + nc4 * 4];
        }
        __syncthreads();
        #pragma unroll
        for (int kk = 0; kk < 32; ++kk) {
            float4 a = *(const float4*)&As[kk][tr * 4];
            float4 b = *(const float4*)&Ws[kk][tc * 4];
            acc[0][0] += a.x * b.x; acc[0][1] += a.x * b.y;
            acc[0][2] += a.x * b.z; acc[0][3] += a.x * b.w;
            acc[1][0] += a.y * b.x; acc[1][1] += a.y * b.y;
            acc[1][2] += a.y * b.z; acc[1][3] += a.y * b.w;
            acc[2][0] += a.z * b.x; acc[2][1] += a.z * b.y;
            acc[2][2] += a.z * b.z; acc[2][3] += a.z * b.w;
            acc[3][0] += a.w * b.x; acc[3][1] += a.w * b.y;
            acc[3][2] += a.w * b.z; acc[3][3] += a.w * b.w;
        }
        __syncthreads();
    }

    float4 bb = *(const float4*)&bias[n0 + tc * 4];
    #pragma unroll
    for (int i = 0; i < 4; ++i) {
        int row = m0 + tr * 4 + i;
        float4 o;
        o.x = acc[i][0] + bb.x;
        o.y = acc[i][1] + bb.y;
        o.z = acc[i][2] + bb.z;
        o.w = acc[i][3] + bb.w;
        if (gelu) {
            o.x = 0.5f * o.x * (1.0f + erff(o.x * 0.70710678118654752f));
            o.y = 0.5f * o.y * (1.0f + erff(o.y * 0.70710678118654752f));
            o.z = 0.5f * o.z * (1.0f + erff(o.z * 0.70710678118654752f));
            o.w = 0.5f * o.w * (1.0f + erff(o.w * 0.70710678118654752f));
        }
        if (R) {
            float4 rv = *(const float4*)&R[(size_t)row * Nn + n0 + tc * 4];
            o.x += rv.x; o.y += rv.y; o.z += rv.z; o.w += rv.w;
        }
        *(float4*)&C[(size_t)row * Nn + n0 + tc * 4] = o;
    }
}

// ---------------------------------------------------------------------------
// Fused top-16 attention: scores + selection + softmax + V-gather.
// Block = 512 threads (8 waves) = 64 queries of one (b,h).
// lane = key; Q staged in LDS once per block, read as same-address BROADCAST
// ds_read (conflict-free, no register array); only one kv float4 live.
// Accumulators a0..a3[8] keep the exact fma order of rounds 1-4 ->
// selection is bit-identical. Top-16 lists lane-distributed (16 slots in 16
// lanes, 2 reg sets x 4 groups = 8 queries/wave); candidates via ballot,
// inserted by a uniform scalar loop (stale-theta extra iterations are
// harmless: INSERT_SLOT re-ballots against current slots, cnt=0 no-ops).
// Register budget ~62 -> no AGPR splitting (rounds 3/4 lesson).
// ---------------------------------------------------------------------------
#define INSERT_SLOT(SLOTV, SLOTI)                                        \
    {                                                                    \
        unsigned long long lt = __ballot(SLOTV < scb);                   \
        int cnt = __popcll((lt >> (gg * 16)) & 0xFFFFull);               \
        if (cnt) {                                                       \
            float shv = __shfl(SLOTV, (lane + 1) & 63);                  \
            int   shi = __shfl(SLOTI, (lane + 1) & 63);                  \
            bool put = ing && (s == cnt - 1);                            \
            bool shf = ing && (s < cnt - 1);                             \
            SLOTV = put ? scb : (shf ? shv : SLOTV);                     \
            SLOTI = put ? idxb : (shf ? shi : SLOTI);                    \
        }                                                                \
    }

__global__ __launch_bounds__(512, 4) void topk_attn_fused(
    const float* __restrict__ Qm, const float* __restrict__ Km,
    const float* __restrict__ Vm, float* __restrict__ Om)
{
    __shared__ float4 Ks4[64 * 16];   // 64 keys   x 16 float4, XOR-swizzled
    __shared__ float4 Qs4[64 * 16];   // 64 queries x 16 float4, linear

    int bid = blockIdx.x;
    int bh  = bid >> 6;               // 0..15
    int qt  = bid & 63;               // query tile within (b,h)
    int b   = bh >> 3, h = bh & 7;
    int qbase = qt * 64;
    int tid  = threadIdx.x;
    int wid  = __builtin_amdgcn_readfirstlane(tid >> 6);  // wave 0..7
    int lane = tid & 63;
    int grp  = lane >> 4;             // slot group 0..3
    int s    = lane & 15;             // slot index within group

    size_t kbase = ((size_t)b * NSEQ) * DIMD + h * HD;

    // Stage this block's 64 q-vectors once.
    #pragma unroll
    for (int qq = 0; qq < 2; ++qq) {
        int idx = tid * 2 + qq;          // 0..1023
        int r   = idx >> 4;              // query row 0..63
        int c4  = idx & 15;
        Qs4[r * 16 + c4] = *(const float4*)
            &Qm[((size_t)(b * NSEQ + qbase + r)) * DIMD + h * HD + c4 * 4];
    }

    float slotvA = -INFINITY, slotvB = -INFINITY;
    int   slotiA = 0,         slotiB = 0;

    for (int t0 = 0; t0 < NSEQ; t0 += 64) {
        __syncthreads();
        #pragma unroll
        for (int qq = 0; qq < 2; ++qq) {
            int idx = tid * 2 + qq;          // 0..1023
            int r   = idx >> 4;              // key row 0..63
            int c4  = idx & 15;
            Ks4[r * 16 + (c4 ^ (r & 15))] =
                *(const float4*)&Km[kbase + (size_t)(t0 + r) * DIMD + c4 * 4];
        }
        __syncthreads();

        // scores for 8 queries, d4-outer: one kv live, q via LDS broadcast
        float a0[8], a1[8], a2[8], a3[8];
        #pragma unroll
        for (int g = 0; g < 8; ++g) { a0[g] = a1[g] = a2[g] = a3[g] = 0.f; }
        #pragma unroll 4
        for (int d4 = 0; d4 < 16; ++d4) {
            float4 kv = Ks4[lane * 16 + (d4 ^ (lane & 15))];
            #pragma unroll
            for (int g = 0; g < 8; ++g) {
                float4 qv = Qs4[(wid * 8 + g) * 16 + d4];   // broadcast read
                a0[g] = fmaf(qv.x, kv.x, a0[g]);
                a1[g] = fmaf(qv.y, kv.y, a1[g]);
                a2[g] = fmaf(qv.z, kv.z, a2[g]);
                a3[g] = fmaf(qv.w, kv.w, a3[g]);
            }
        }

        #pragma unroll
        for (int g = 0; g < 8; ++g) {
            float sc = ((a0[g] + a1[g]) + (a2[g] + a3[g])) * 0.125f;
            int gg = g & 3;
            bool ing = (grp == gg);
            float theta = __shfl((g < 4) ? slotvA : slotvB, gg * 16);
            unsigned long long cand = __ballot(sc > theta);
            while (cand) {                    // uniform scalar loop
                int src = __ffsll(cand) - 1;
                cand &= cand - 1;
                float scb  = __shfl(sc, src); // ascending key order -> stable
                int   idxb = t0 + src;
                if (g < 4) INSERT_SLOT(slotvA, slotiA)
                else       INSERT_SLOT(slotvB, slotiB)
            }
        }
    }

    // ---- softmax + V-gather, set A (queries g=0..3) then set B (4..7) ----
    #pragma unroll
    for (int set = 0; set < 2; ++set) {
        float slotv = set ? slotvB : slotvA;
        int   sloti = set ? slotiB : slotiA;
        float mx = __shfl(slotv, (lane & 48) + 15);   // per-group max
        float w  = expf(slotv - mx);
        float ssum = w;
        #pragma unroll
        for (int off = 1; off < 16; off <<= 1) ssum += __shfl_xor(ssum, off);
        float wn = w * (1.0f / ssum);

        #pragma unroll
        for (int gg2 = 0; gg2 < 4; ++gg2) {
            float acc = 0.f;
            #pragma unroll
            for (int i = 15; i >= 0; --i) {   // descending = ref's topk order
                float wi = __shfl(wn, gg2 * 16 + i);
                int   ki = __shfl(sloti, gg2 * 16 + i);
                acc = fmaf(wi, Vm[((size_t)(b * NSEQ + ki)) * DIMD + h * HD + lane], acc);
            }
            int qn = qbase + wid * 8 + set * 4 + gg2;
            Om[((size_t)(b * NSEQ + qn)) * DIMD + h * HD + lane] = acc;
        }
    }
}

// ---------------------------------------------------------------------------
extern "C" void kernel_launch(void* const* d_in, const int* in_sizes, int n_in,
                              void* d_out, int out_size, void* d_ws, size_t ws_size,
                              hipStream_t stream)
{
    (void)in_sizes; (void)n_in; (void)out_size; (void)ws_size;
    const float* x    = (const float*)d_in[0];
    const float* q_w  = (const float*)d_in[1];
    const float* q_b  = (const float*)d_in[2];
    const float* k_w  = (const float*)d_in[3];
    const float* k_b  = (const float*)d_in[4];
    const float* v_w  = (const float*)d_in[5];
    const float* v_b  = (const float*)d_in[6];
    const float* o_w  = (const float*)d_in[7];
    const float* o_b  = (const float*)d_in[8];
    const float* ln1g = (const float*)d_in[9];
    const float* ln1b = (const float*)d_in[10];
    const float* ln2g = (const float*)d_in[11];
    const float* ln2b = (const float*)d_in[12];
    const float* ff1w = (const float*)d_in[13];
    const float* ff1b = (const float*)d_in[14];
    const float* ff2w = (const float*)d_in[15];
    const float* ff2b = (const float*)d_in[16];
    float* out = (float*)d_out;
    float* ws  = (float*)d_ws;

    const size_t SZ = (size_t)8192 * DIMD;   // 4M floats = 16 MiB
    float*  Qb      = ws;                    // [8192 x 512]
    float*  Kb      = ws + SZ;
    float*  Vb      = ws + 2 * SZ;
    float*  attnOut = ws + 3 * SZ;           // [8192 x 512]
    float2* stats   = (float2*)(ws + 4 * SZ);
    float*  ffb     = ws;                    // [8192 x 2048], reuses ws

    dim3 g512(8, 128);    // Nn/64, M/64

    // LN1 stats, then Q/K/V projections with LN fused into the A-load.
    ln_stats_kernel<<<8192, 256, 0, stream>>>(x, stats);
    gemm_f32<<<g512, 256, 0, stream>>>(x, q_w, q_b, nullptr, Qb,
                                       512, 512, 0, stats, ln1g, ln1b);
    gemm_f32<<<g512, 256, 0, stream>>>(x, k_w, k_b, nullptr, Kb,
                                       512, 512, 0, stats, ln1g, ln1b);
    gemm_f32<<<g512, 256, 0, stream>>>(x, v_w, v_b, nullptr, Vb,
                                       512, 512, 0, stats, ln1g, ln1b);

    // Fused top-16 attention (scores + select + softmax + gather).
    topk_attn_fused<<<1024, 512, 0, stream>>>(Qb, Kb, Vb, attnOut);

    // x2 = x + attnOut @ o_w + o_b   -> d_out
    gemm_f32<<<g512, 256, 0, stream>>>(attnOut, o_w, o_b, x, out,
                                       512, 512, 0, nullptr, nullptr, nullptr);

    // LN2 stats from x2, FFN with LN fused; ff1 -> ffb (gelu), then
    // out = x2 + ffb @ ff2_w + ff2_b (in-place residual on d_out).
    ln_stats_kernel<<<8192, 256, 0, stream>>>(out, stats);
    gemm_f32<<<dim3(32, 128), 256, 0, stream>>>(out, ff1w, ff1b, nullptr, ffb,
                                                512, 2048, 1, stats, ln2g, ln2b);
    gemm_f32<<<g512, 256, 0, stream>>>(ffb, ff2w, ff2b, out, out,
                                       2048, 512, 0, nullptr, nullptr, nullptr);
}